// Round 3
// baseline (298.575 us; speedup 1.0000x reference)
//
#include <hip/hip_runtime.h>
#include <hip/hip_bf16.h>

using short8 = __attribute__((ext_vector_type(8))) short;
using f32x4  = __attribute__((ext_vector_type(4))) float;

#define MBATCH 16
#define NUMV   128
#define LEN    64
#define SZ     256

__device__ __forceinline__ unsigned short bfbits(float x) {
  union { float f; unsigned u; } c; c.f = x;
  return (unsigned short)((c.u + 0x8000u) >> 16);   // round-to-nearest
}

// ---------------- prep 1: u[bn][s], v[bn][s] (layer-1 factorization) ----------------
__global__ void uv_prep(const float* __restrict__ in_, const float* __restrict__ W1,
                        const float* __restrict__ b1,
                        float* __restrict__ u, float* __restrict__ v) {
  int bn = blockIdx.x;
  int n  = bn & (NUMV - 1);
  int s  = threadIdx.x;                // 256 threads
  __shared__ float xs[LEN];
  if (s < LEN) xs[s] = in_[bn * LEN + s];
  __syncthreads();
  float fn = (float)n;
  float uu = fn * W1[64 * SZ + s];
  float vv = fn * W1[129 * SZ + s] + b1[s];
  for (int c = 0; c < LEN; ++c) {
    uu = fmaf(xs[c], W1[c * SZ + s], uu);
    vv = fmaf(xs[c], W1[(65 + c) * SZ + s], vv);
  }
  u[bn * SZ + s] = uu;
  v[bn * SZ + s] = vv;
}

// ---------------- prep 2: W2/W3/W4 -> bf16, transposed, fragment-ordered, bank-swizzled ----
// chunk kb holds K=32: slot = (c*4 + q) ^ (c&7); 16B at slot = Wt[c][kb*32 + q*8 .. +7]
__global__ void w_prep(const float* __restrict__ W2, const float* __restrict__ W3,
                       const float* __restrict__ W4, short* __restrict__ wlay) {
  int L = blockIdx.x >> 3, kb = blockIdx.x & 7;     // 24 blocks
  const float* W = (L == 0) ? W2 : (L == 1) ? W3 : W4;
  int c = threadIdx.x;                              // 256 threads
  short* dst = wlay + L * 65536 + kb * 8192;
  for (int qq = 0; qq < 4; ++qq) {
    short8 pk;
    for (int i = 0; i < 8; ++i)
      pk[i] = (short)bfbits(W[(kb * 32 + qq * 8 + i) * SZ + c]);
    int slot = (c * 4 + qq) ^ (c & 7);
    *reinterpret_cast<short8*>(dst + slot * 8) = pk;
  }
}

// ---------------- main fused kernel ----------------
// One WG per (b, a): 128 rows (all j), 256 threads = 4 waves.
// Wave tile 128ch x 64rows (8 M-frags x 4 N-frags of 16x16x32) -> 42.7 FLOP/LDS-byte.
// LDS = 64KB hbuf (512B stride + XOR swizzle) + 16KB wbuf = 80KB -> 2 blocks/CU.
__global__ __launch_bounds__(256, 2) void fused_mlp(
    const float* __restrict__ u, const float* __restrict__ v,
    const short* __restrict__ wlay,
    const float* __restrict__ b2, const float* __restrict__ b3, const float* __restrict__ b4,
    float* __restrict__ partial) {
  __shared__ __align__(16) char smem[81920];
  short* hbuf = (short*)smem;                 // [128][256] bf16, byte ^= (row&7)<<4
  short* wbuf = (short*)(smem + 65536);       // one 16KB K32 chunk
  float* pbuf = (float*)(smem + 65536);       // alias, used after last wbuf read

  int wg = blockIdx.x;
  int b = wg >> 7, a = wg & 127;
  int tid = threadIdx.x;

  // ---- h1 = relu(u[b,j] + v[b,a]) -> bf16, swizzled row-major in LDS ----
  {
    const float4* ub = (const float4*)(u + (size_t)b * NUMV * SZ);
    const float4* vb = (const float4*)(v + ((size_t)b * NUMV + a) * SZ);
    #pragma unroll
    for (int it = 0; it < 32; ++it) {
      int flat = tid + it * 256;          // over 128 rows * 64 col-quads
      int j = flat >> 6, c4 = flat & 63;
      float4 uu = ub[j * 64 + c4];
      float4 vv = vb[c4];
      unsigned lo = (unsigned)bfbits(fmaxf(uu.x + vv.x, 0.f))
                  | ((unsigned)bfbits(fmaxf(uu.y + vv.y, 0.f)) << 16);
      unsigned hi = (unsigned)bfbits(fmaxf(uu.z + vv.z, 0.f))
                  | ((unsigned)bfbits(fmaxf(uu.w + vv.w, 0.f)) << 16);
      int byte = (j * 512 + c4 * 8) ^ ((j & 7) << 4);
      uint2 pk; pk.x = lo; pk.y = hi;
      *reinterpret_cast<uint2*>((char*)hbuf + byte) = pk;
    }
  }

  int wave = tid >> 6, lane = tid & 63;
  int l16 = lane & 15, q = lane >> 4;
  int wM = wave & 1, wN = wave >> 1;

  const float* biases[3] = { b2, b3, b4 };
  const char* wl = (const char*)wlay;
  short8 t0, t1, t2, t3;

  #define LOADW(off) { const short8* g = (const short8*)(wl + (off)); \
      t0 = g[tid]; t1 = g[256 + tid]; t2 = g[512 + tid]; t3 = g[768 + tid]; }
  #define WRITEW() { short8* d = (short8*)wbuf; \
      d[tid] = t0; d[256 + tid] = t1; d[512 + tid] = t2; d[768 + tid] = t3; }

  LOADW(0);
  __syncthreads();          // h1 stores done + chunk0 loads landed (vmcnt drain)
  WRITEW();
  __syncthreads();
  LOADW(16384);

  for (int L = 0; L < 3; ++L) {
    f32x4 acc[8][4];
    #pragma unroll
    for (int m = 0; m < 8; ++m)
      #pragma unroll
      for (int n = 0; n < 4; ++n)
        acc[m][n] = f32x4{0.f, 0.f, 0.f, 0.f};

    for (int kb = 0; kb < 8; ++kb) {
      short8 af[8], bfr[4];
      #pragma unroll
      for (int m = 0; m < 8; ++m) {
        int ch = wM * 128 + m * 16 + l16;
        int slot = (ch * 4 + q) ^ (ch & 7);
        af[m] = *reinterpret_cast<const short8*>(wbuf + slot * 8);
      }
      #pragma unroll
      for (int n = 0; n < 4; ++n) {
        int row = wN * 64 + n * 16 + l16;
        int byte = (row * 512 + kb * 64 + q * 16) ^ ((row & 7) << 4);
        bfr[n] = *reinterpret_cast<const short8*>((char*)hbuf + byte);
      }
      __builtin_amdgcn_s_setprio(1);
      #pragma unroll
      for (int m = 0; m < 8; ++m)
        #pragma unroll
        for (int n = 0; n < 4; ++n)
          acc[m][n] = __builtin_amdgcn_mfma_f32_16x16x32_bf16(af[m], bfr[n], acc[m][n], 0, 0, 0);
      __builtin_amdgcn_s_setprio(0);
      __syncthreads();                   // all wbuf/hbuf reads done (MFMA drains past it)
      if (kb < 7) {
        WRITEW();                        // chunk kb+1 (loads drained by barrier above)
        if (kb < 6) LOADW(L * 131072 + (kb + 2) * 16384);
        __syncthreads();                 // chunk kb+1 visible
      }
    }

    if (L < 2) {
      LOADW((L + 1) * 131072);           // next layer chunk0 (hide under epilogue)
      const float* bb = biases[L];
      #pragma unroll
      for (int m = 0; m < 8; ++m) {
        f32x4 bv = *reinterpret_cast<const f32x4*>(bb + wM * 128 + m * 16 + q * 4);
        int ch = wM * 128 + m * 16 + q * 4;
        #pragma unroll
        for (int n = 0; n < 4; ++n) {
          int row = wN * 64 + n * 16 + l16;
          f32x4 t = acc[m][n];
          unsigned lo = (unsigned)bfbits(fmaxf(t[0] + bv[0], 0.f))
                      | ((unsigned)bfbits(fmaxf(t[1] + bv[1], 0.f)) << 16);
          unsigned hi = (unsigned)bfbits(fmaxf(t[2] + bv[2], 0.f))
                      | ((unsigned)bfbits(fmaxf(t[3] + bv[3], 0.f)) << 16);
          int byte = (row * 512 + ch * 2) ^ ((row & 7) << 4);
          uint2 pk; pk.x = lo; pk.y = hi;
          *reinterpret_cast<uint2*>((char*)hbuf + byte) = pk;
        }
      }
      WRITEW();                          // next layer chunk0 -> wbuf
      __syncthreads();                   // h_next + chunk0 visible
      LOADW((L + 1) * 131072 + 16384);   // next layer chunk1
    } else {
      // final layer: relu+bias, sum over this wave's 64 rows, then cross-wave via pbuf
      const float* bb = biases[2];
      #pragma unroll
      for (int m = 0; m < 8; ++m) {
        f32x4 bv = *reinterpret_cast<const f32x4*>(bb + wM * 128 + m * 16 + q * 4);
        f32x4 s = f32x4{0.f, 0.f, 0.f, 0.f};
        #pragma unroll
        for (int n = 0; n < 4; ++n) {
          s[0] += fmaxf(acc[m][n][0] + bv[0], 0.f);
          s[1] += fmaxf(acc[m][n][1] + bv[1], 0.f);
          s[2] += fmaxf(acc[m][n][2] + bv[2], 0.f);
          s[3] += fmaxf(acc[m][n][3] + bv[3], 0.f);
        }
        #pragma unroll
        for (int r = 0; r < 4; ++r) {
          float x = s[r];
          x += __shfl_xor(x, 1);
          x += __shfl_xor(x, 2);
          x += __shfl_xor(x, 4);
          x += __shfl_xor(x, 8);
          if (l16 == 0) pbuf[wN * 256 + wM * 128 + m * 16 + q * 4 + r] = x;
        }
      }
      __syncthreads();
      partial[(size_t)wg * SZ + tid] = pbuf[tid] + pbuf[256 + tid];
    }
  }
  #undef LOADW
  #undef WRITEW
}

// ---------------- final reduction over a ----------------
__global__ void reduce_partials(const float* __restrict__ partial, float* __restrict__ out) {
  int b = blockIdx.x;            // 16 blocks x 256 threads
  int s = threadIdx.x;
  const float* p = partial + (size_t)b * NUMV * SZ + s;
  float acc = 0.f;
  for (int i = 0; i < NUMV; ++i) acc += p[(size_t)i * SZ];
  out[b * SZ + s] = acc;
}

extern "C" void kernel_launch(void* const* d_in, const int* in_sizes, int n_in,
                              void* d_out, int out_size, void* d_ws, size_t ws_size,
                              hipStream_t stream) {
  const float* in_ = (const float*)d_in[0];
  const float* W1  = (const float*)d_in[1];
  const float* b1  = (const float*)d_in[2];
  const float* W2  = (const float*)d_in[3];
  const float* b2  = (const float*)d_in[4];
  const float* W3  = (const float*)d_in[5];
  const float* b3  = (const float*)d_in[6];
  const float* W4  = (const float*)d_in[7];
  const float* b4  = (const float*)d_in[8];
  float* out = (float*)d_out;

  char* ws = (char*)d_ws;
  float* u       = (float*)(ws);                                 // 2 MB
  float* v       = (float*)(ws + (2u << 20));                    // 2 MB
  short* wlay    = (short*)(ws + (4u << 20));                    // 384 KB
  float* partial = (float*)(ws + (4u << 20) + (1u << 19));       // 2 MB

  uv_prep<<<MBATCH * NUMV, 256, 0, stream>>>(in_, W1, b1, u, v);
  w_prep<<<24, 256, 0, stream>>>(W2, W3, W4, wlay);
  fused_mlp<<<MBATCH * NUMV, 256, 0, stream>>>(u, v, wlay, b2, b3, b4, partial);
  reduce_partials<<<MBATCH, 256, 0, stream>>>(partial, out);
}

// Round 4
// 247.886 us; speedup vs baseline: 1.2045x; 1.2045x over previous
//
#include <hip/hip_runtime.h>
#include <hip/hip_bf16.h>

using short8 = __attribute__((ext_vector_type(8))) short;
using f32x4  = __attribute__((ext_vector_type(4))) float;

#define MBATCH 16
#define NUMV   128
#define LEN    64
#define SZ     256

__device__ __forceinline__ unsigned short bfbits(float x) {
  union { float f; unsigned u; } c; c.f = x;
  return (unsigned short)((c.u + 0x8000u) >> 16);   // round-to-nearest
}

typedef const unsigned char __attribute__((address_space(1))) gu8;
typedef unsigned char __attribute__((address_space(3))) lu8;
__device__ __forceinline__ void gload_lds16(const void* g, void* l) {
  // dest = (wave-uniform l) + lane*16 ; src = per-lane g
  __builtin_amdgcn_global_load_lds((gu8*)g, (lu8*)l, 16, 0, 0);
}

// ---------------- prep 1: u[bn][s], v[bn][s] (layer-1 factorization) ----------------
__global__ void uv_prep(const float* __restrict__ in_, const float* __restrict__ W1,
                        const float* __restrict__ b1,
                        float* __restrict__ u, float* __restrict__ v) {
  int bn = blockIdx.x;
  int n  = bn & (NUMV - 1);
  int s  = threadIdx.x;                // 256 threads
  __shared__ float xs[LEN];
  if (s < LEN) xs[s] = in_[bn * LEN + s];
  __syncthreads();
  float fn = (float)n;
  float uu = fn * W1[64 * SZ + s];
  float vv = fn * W1[129 * SZ + s] + b1[s];
  for (int c = 0; c < LEN; ++c) {
    uu = fmaf(xs[c], W1[c * SZ + s], uu);
    vv = fmaf(xs[c], W1[(65 + c) * SZ + s], vv);
  }
  u[bn * SZ + s] = uu;
  v[bn * SZ + s] = vv;
}

// ---------------- prep 2: W2/W3/W4 -> bf16, transposed, fragment-ordered, bank-swizzled ----
// chunk kb holds K=32: slot = (c*4 + q) ^ (c&7); 16B at slot = Wt[c][kb*32 + q*8 .. +7]
__global__ void w_prep(const float* __restrict__ W2, const float* __restrict__ W3,
                       const float* __restrict__ W4, short* __restrict__ wlay) {
  int L = blockIdx.x >> 3, kb = blockIdx.x & 7;     // 24 blocks
  const float* W = (L == 0) ? W2 : (L == 1) ? W3 : W4;
  int c = threadIdx.x;                              // 256 threads
  short* dst = wlay + L * 65536 + kb * 8192;
  for (int qq = 0; qq < 4; ++qq) {
    short8 pk;
    for (int i = 0; i < 8; ++i)
      pk[i] = (short)bfbits(W[(kb * 32 + qq * 8 + i) * SZ + c]);
    int slot = (c * 4 + qq) ^ (c & 7);
    *reinterpret_cast<short8*>(dst + slot * 8) = pk;
  }
}

// ---------------- main fused kernel ----------------
// One WG per (b, a): 128 rows (all j), 256 threads = 4 waves.
// Wave tile 128ch x 64rows (8 M x 4 N frags of 16x16x32) -> 42.7 FLOP/LDS-byte.
// Weights staged via global_load_lds (zero VGPR cost). LDS = 64K hbuf + 16K wbuf = 80K
// -> 2 blocks/CU; the two blocks overlap each other's barriers/DMA latency.
__global__ __launch_bounds__(256, 2) void fused_mlp(
    const float* __restrict__ u, const float* __restrict__ v,
    const short* __restrict__ wlay,
    const float* __restrict__ b2, const float* __restrict__ b3, const float* __restrict__ b4,
    float* __restrict__ partial) {
  __shared__ __align__(16) char smem[81920];
  short* hbuf = (short*)smem;                 // [128][256] bf16, byte ^= (row&7)<<4
  short* wbuf = (short*)(smem + 65536);       // one 16KB K32 chunk
  float* pbuf = (float*)(smem + 65536);       // alias, used after last wbuf read

  int wg = blockIdx.x;
  int b = wg >> 7, a = wg & 127;
  int tid = threadIdx.x;
  int wave = tid >> 6, lane = tid & 63;

  const char* wl0 = (const char*)wlay;

  #define GLOAD(off) { \
    const char* g = wl0 + (off) + wave * 4096 + lane * 16; \
    char* d = (char*)wbuf + wave * 4096; \
    gload_lds16(g, d); \
    gload_lds16(g + 1024, d + 1024); \
    gload_lds16(g + 2048, d + 2048); \
    gload_lds16(g + 3072, d + 3072); }

  GLOAD(0);                                  // layer-0 chunk-0 in flight

  // ---- h1 = relu(u[b,j] + v[b,a]) -> bf16, swizzled row-major in LDS ----
  {
    const float4* ub = (const float4*)(u + (size_t)b * NUMV * SZ);
    const float4* vb = (const float4*)(v + ((size_t)b * NUMV + a) * SZ);
    #pragma unroll
    for (int it = 0; it < 32; ++it) {
      int flat = tid + it * 256;          // over 128 rows * 64 col-quads
      int j = flat >> 6, c4 = flat & 63;
      float4 uu = ub[j * 64 + c4];
      float4 vv = vb[c4];
      unsigned lo = (unsigned)bfbits(fmaxf(uu.x + vv.x, 0.f))
                  | ((unsigned)bfbits(fmaxf(uu.y + vv.y, 0.f)) << 16);
      unsigned hi = (unsigned)bfbits(fmaxf(uu.z + vv.z, 0.f))
                  | ((unsigned)bfbits(fmaxf(uu.w + vv.w, 0.f)) << 16);
      int byte = (j * 512 + c4 * 8) ^ ((j & 7) << 4);
      uint2 pk; pk.x = lo; pk.y = hi;
      *reinterpret_cast<uint2*>((char*)hbuf + byte) = pk;
    }
  }

  int l16 = lane & 15, q = lane >> 4;
  int wM = wave & 1, wN = wave >> 1;
  const float* biases[3] = { b2, b3, b4 };

  __syncthreads();        // h1 stores + chunk0 DMA drained

  for (int L = 0; L < 3; ++L) {
    f32x4 acc[8][4];
    #pragma unroll
    for (int m = 0; m < 8; ++m)
      #pragma unroll
      for (int n = 0; n < 4; ++n)
        acc[m][n] = f32x4{0.f, 0.f, 0.f, 0.f};

    for (int kb = 0; kb < 8; ++kb) {
      short8 af[8], bfr[4];
      #pragma unroll
      for (int m = 0; m < 8; ++m) {
        int ch = wM * 128 + m * 16 + l16;
        int slot = (ch * 4 + q) ^ (ch & 7);
        af[m] = *reinterpret_cast<const short8*>(wbuf + slot * 8);
      }
      #pragma unroll
      for (int n = 0; n < 4; ++n) {
        int row = wN * 64 + n * 16 + l16;
        int byte = (row * 512 + kb * 64 + q * 16) ^ ((row & 7) << 4);
        bfr[n] = *reinterpret_cast<const short8*>((char*)hbuf + byte);
      }
      __syncthreads();    // sync1: all waves' wbuf/hbuf reads complete

      if (kb < 7)      GLOAD(L * 131072 + (kb + 1) * 16384)   // next chunk DMA
      else if (L < 2)  GLOAD((L + 1) * 131072);               // next layer chunk0

      __builtin_amdgcn_s_setprio(1);
      #pragma unroll
      for (int m = 0; m < 8; ++m)
        #pragma unroll
        for (int n = 0; n < 4; ++n)
          acc[m][n] = __builtin_amdgcn_mfma_f32_16x16x32_bf16(af[m], bfr[n], acc[m][n], 0, 0, 0);
      __builtin_amdgcn_s_setprio(0);

      if (L < 2 && kb == 7) {
        // epilogue: h_next[row][ch] relu+bias -> swizzled hbuf (reads done since sync1)
        const float* bb = biases[L];
        #pragma unroll
        for (int m = 0; m < 8; ++m) {
          f32x4 bv = *reinterpret_cast<const f32x4*>(bb + wM * 128 + m * 16 + q * 4);
          int ch = wM * 128 + m * 16 + q * 4;
          #pragma unroll
          for (int n = 0; n < 4; ++n) {
            int row = wN * 64 + n * 16 + l16;
            f32x4 t = acc[m][n];
            unsigned lo = (unsigned)bfbits(fmaxf(t[0] + bv[0], 0.f))
                        | ((unsigned)bfbits(fmaxf(t[1] + bv[1], 0.f)) << 16);
            unsigned hi = (unsigned)bfbits(fmaxf(t[2] + bv[2], 0.f))
                        | ((unsigned)bfbits(fmaxf(t[3] + bv[3], 0.f)) << 16);
            int byte = (row * 512 + ch * 2) ^ ((row & 7) << 4);
            uint2 pk; pk.x = lo; pk.y = hi;
            *reinterpret_cast<uint2*>((char*)hbuf + byte) = pk;
          }
        }
      }
      __syncthreads();    // sync2: DMA chunk + h_next visible
    }

    if (L == 2) {
      // final layer: relu+bias, sum over this wave's 64 rows, cross-wave via pbuf
      const float* bb = biases[2];
      #pragma unroll
      for (int m = 0; m < 8; ++m) {
        f32x4 bv = *reinterpret_cast<const f32x4*>(bb + wM * 128 + m * 16 + q * 4);
        f32x4 s = f32x4{0.f, 0.f, 0.f, 0.f};
        #pragma unroll
        for (int n = 0; n < 4; ++n) {
          s[0] += fmaxf(acc[m][n][0] + bv[0], 0.f);
          s[1] += fmaxf(acc[m][n][1] + bv[1], 0.f);
          s[2] += fmaxf(acc[m][n][2] + bv[2], 0.f);
          s[3] += fmaxf(acc[m][n][3] + bv[3], 0.f);
        }
        #pragma unroll
        for (int r = 0; r < 4; ++r) {
          float x = s[r];
          x += __shfl_xor(x, 1);
          x += __shfl_xor(x, 2);
          x += __shfl_xor(x, 4);
          x += __shfl_xor(x, 8);
          if (l16 == 0) pbuf[wN * 256 + wM * 128 + m * 16 + q * 4 + r] = x;
        }
      }
      __syncthreads();
      partial[(size_t)wg * SZ + tid] = pbuf[tid] + pbuf[256 + tid];
    }
  }
  #undef GLOAD
}

// ---------------- final reduction over a ----------------
__global__ void reduce_partials(const float* __restrict__ partial, float* __restrict__ out) {
  int b = blockIdx.x;            // 16 blocks x 256 threads
  int s = threadIdx.x;
  const float* p = partial + (size_t)b * NUMV * SZ + s;
  float acc = 0.f;
  for (int i = 0; i < NUMV; ++i) acc += p[(size_t)i * SZ];
  out[b * SZ + s] = acc;
}

extern "C" void kernel_launch(void* const* d_in, const int* in_sizes, int n_in,
                              void* d_out, int out_size, void* d_ws, size_t ws_size,
                              hipStream_t stream) {
  const float* in_ = (const float*)d_in[0];
  const float* W1  = (const float*)d_in[1];
  const float* b1  = (const float*)d_in[2];
  const float* W2  = (const float*)d_in[3];
  const float* b2  = (const float*)d_in[4];
  const float* W3  = (const float*)d_in[5];
  const float* b3  = (const float*)d_in[6];
  const float* W4  = (const float*)d_in[7];
  const float* b4  = (const float*)d_in[8];
  float* out = (float*)d_out;

  char* ws = (char*)d_ws;
  float* u       = (float*)(ws);                                 // 2 MB
  float* v       = (float*)(ws + (2u << 20));                    // 2 MB
  short* wlay    = (short*)(ws + (4u << 20));                    // 384 KB
  float* partial = (float*)(ws + (4u << 20) + (1u << 19));       // 2 MB

  uv_prep<<<MBATCH * NUMV, 256, 0, stream>>>(in_, W1, b1, u, v);
  w_prep<<<24, 256, 0, stream>>>(W2, W3, W4, wlay);
  fused_mlp<<<MBATCH * NUMV, 256, 0, stream>>>(u, v, wlay, b2, b3, b4, partial);
  reduce_partials<<<MBATCH, 256, 0, stream>>>(partial, out);
}

// Round 5
// 149.512 us; speedup vs baseline: 1.9970x; 1.6580x over previous
//
#include <hip/hip_runtime.h>
#include <hip/hip_bf16.h>

using short8 = __attribute__((ext_vector_type(8))) short;
using f32x4  = __attribute__((ext_vector_type(4))) float;

#define MBATCH 16
#define NUMV   128
#define LEN    64
#define SZ     256

__device__ __forceinline__ unsigned short bfbits(float x) {
  union { float f; unsigned u; } c; c.f = x;
  return (unsigned short)((c.u + 0x8000u) >> 16);   // round-to-nearest
}

typedef const unsigned char __attribute__((address_space(1))) gu8;
typedef unsigned char __attribute__((address_space(3))) lu8;
__device__ __forceinline__ void gload_lds16(const void* g, void* l) {
  // dest = (wave-uniform l) + lane*16 ; src = per-lane g
  __builtin_amdgcn_global_load_lds((gu8*)g, (lu8*)l, 16, 0, 0);
}

// ---------------- prep 1: u[bn][s], v[bn][s] (layer-1 factorization) ----------------
__global__ void uv_prep(const float* __restrict__ in_, const float* __restrict__ W1,
                        const float* __restrict__ b1,
                        float* __restrict__ u, float* __restrict__ v) {
  int bn = blockIdx.x;
  int n  = bn & (NUMV - 1);
  int s  = threadIdx.x;                // 256 threads
  __shared__ float xs[LEN];
  if (s < LEN) xs[s] = in_[bn * LEN + s];
  __syncthreads();
  float fn = (float)n;
  float uu = fn * W1[64 * SZ + s];
  float vv = fn * W1[129 * SZ + s] + b1[s];
  for (int c = 0; c < LEN; ++c) {
    uu = fmaf(xs[c], W1[c * SZ + s], uu);
    vv = fmaf(xs[c], W1[(65 + c) * SZ + s], vv);
  }
  u[bn * SZ + s] = uu;
  v[bn * SZ + s] = vv;
}

// ---------------- prep 2: W2/W3/W4 -> bf16, transposed, fragment-ordered, bank-swizzled ----
// 24 linear 16KB chunks (ci = L*8+kb), K=32 each: slot = (c*4 + q) ^ (c&7);
// 16B at slot = Wt[c][kb*32 + q*8 .. +7]
__global__ void w_prep(const float* __restrict__ W2, const float* __restrict__ W3,
                       const float* __restrict__ W4, short* __restrict__ wlay) {
  int L = blockIdx.x >> 3, kb = blockIdx.x & 7;     // 24 blocks
  const float* W = (L == 0) ? W2 : (L == 1) ? W3 : W4;
  int c = threadIdx.x;                              // 256 threads
  short* dst = wlay + L * 65536 + kb * 8192;
  for (int qq = 0; qq < 4; ++qq) {
    short8 pk;
    for (int i = 0; i < 8; ++i)
      pk[i] = (short)bfbits(W[(kb * 32 + qq * 8 + i) * SZ + c]);
    int slot = (c * 4 + qq) ^ (c & 7);
    *reinterpret_cast<short8*>(dst + slot * 8) = pk;
  }
}

// ---------------- main fused kernel ----------------
// One WG per (b, a, jhalf): 64 rows, 256 threads = 4 waves.
// Wave w owns output channels w*64..w*64+63 (M=4 frags) x all 64 rows (N=4 frags).
// acc[4][4]=64 regs + af[4]+bfr[4]=32 -> ~130 regs, zero spill at 256-budget.
// LDS = 32KB hbuf (XOR swizzle) + 2x16KB wbuf dbuf = 64KB -> 2 blocks/CU.
// One barrier per kb-step: DMA chunk ci+1 -> buf^1 overlaps MFMA on buf.
__global__ __launch_bounds__(256, 2) void fused_mlp(
    const float* __restrict__ u, const float* __restrict__ v,
    const short* __restrict__ wlay,
    const float* __restrict__ b2, const float* __restrict__ b3, const float* __restrict__ b4,
    float* __restrict__ partial) {
  __shared__ __align__(16) char smem[65536];
  short* hbuf = (short*)smem;                 // [64][256] bf16, byte ^= (row&7)<<4
  short* wbuf = (short*)(smem + 32768);       // 2 x 16KB K32 chunks

  int wg = blockIdx.x;
  int b = wg >> 8, a = (wg >> 1) & 127, jh = wg & 1;
  int tid = threadIdx.x;
  int wave = tid >> 6, lane = tid & 63;

  const char* wl0 = (const char*)wlay;

  #define GLOAD(ci) { \
    const char* g = wl0 + (ci) * 16384 + wave * 4096 + lane * 16; \
    char* d = (char*)wbuf + ((ci) & 1) * 16384 + wave * 4096; \
    gload_lds16(g, d); \
    gload_lds16(g + 1024, d + 1024); \
    gload_lds16(g + 2048, d + 2048); \
    gload_lds16(g + 3072, d + 3072); }

  GLOAD(0);                                  // chunk 0 in flight under h1 math

  // ---- h1 = relu(u[b,j] + v[b,a]) -> bf16, swizzled row-major in LDS ----
  {
    const float4* ub = (const float4*)(u + (size_t)b * NUMV * SZ) + jh * 64 * 64;
    const float4* vb = (const float4*)(v + ((size_t)b * NUMV + a) * SZ);
    #pragma unroll
    for (int it = 0; it < 16; ++it) {
      int flat = tid + it * 256;          // over 64 rows * 64 col-quads
      int jr = flat >> 6, c4 = flat & 63;
      float4 uu = ub[jr * 64 + c4];
      float4 vv = vb[c4];
      unsigned lo = (unsigned)bfbits(fmaxf(uu.x + vv.x, 0.f))
                  | ((unsigned)bfbits(fmaxf(uu.y + vv.y, 0.f)) << 16);
      unsigned hi = (unsigned)bfbits(fmaxf(uu.z + vv.z, 0.f))
                  | ((unsigned)bfbits(fmaxf(uu.w + vv.w, 0.f)) << 16);
      int byte = (jr * 512 + c4 * 8) ^ ((jr & 7) << 4);
      uint2 pk; pk.x = lo; pk.y = hi;
      *reinterpret_cast<uint2*>((char*)hbuf + byte) = pk;
    }
  }

  int l16 = lane & 15, q = lane >> 4;

  __syncthreads();        // h1 stores done + chunk0 DMA drained

  #pragma unroll
  for (int L = 0; L < 3; ++L) {
    const float* bb = (L == 0) ? b2 : (L == 1) ? b3 : b4;

    f32x4 acc[4][4];
    #pragma unroll
    for (int m = 0; m < 4; ++m)
      #pragma unroll
      for (int n = 0; n < 4; ++n)
        acc[m][n] = f32x4{0.f, 0.f, 0.f, 0.f};

    #pragma unroll
    for (int kb = 0; kb < 8; ++kb) {
      int ci = L * 8 + kb;
      const short* wb = wbuf + (ci & 1) * 8192;
      short8 af[4], bfr[4];
      #pragma unroll
      for (int m = 0; m < 4; ++m) {
        int ch = wave * 64 + m * 16 + l16;
        int slot = (ch * 4 + q) ^ (ch & 7);
        af[m] = *reinterpret_cast<const short8*>(wb + slot * 8);
      }
      #pragma unroll
      for (int n = 0; n < 4; ++n) {
        int row = n * 16 + l16;
        int byte = (row * 512 + kb * 64 + q * 16) ^ ((row & 7) << 4);
        bfr[n] = *reinterpret_cast<const short8*>((char*)hbuf + byte);
      }
      if (ci < 23) GLOAD(ci + 1);          // next chunk -> other buffer, hides under MFMA
      __builtin_amdgcn_s_setprio(1);
      #pragma unroll
      for (int m = 0; m < 4; ++m)
        #pragma unroll
        for (int n = 0; n < 4; ++n)
          acc[m][n] = __builtin_amdgcn_mfma_f32_16x16x32_bf16(af[m], bfr[n], acc[m][n], 0, 0, 0);
      __builtin_amdgcn_s_setprio(0);
      __syncthreads();    // reads of cur done everywhere + DMA chunk ci+1 landed
    }

    if (L < 2) {
      // epilogue: h_next[row][ch] = relu(acc+bias) -> swizzled hbuf, in place
      #pragma unroll
      for (int m = 0; m < 4; ++m) {
        f32x4 bv = *reinterpret_cast<const f32x4*>(bb + wave * 64 + m * 16 + q * 4);
        int ch = wave * 64 + m * 16 + q * 4;
        #pragma unroll
        for (int n = 0; n < 4; ++n) {
          int row = n * 16 + l16;
          f32x4 t = acc[m][n];
          unsigned lo = (unsigned)bfbits(fmaxf(t[0] + bv[0], 0.f))
                      | ((unsigned)bfbits(fmaxf(t[1] + bv[1], 0.f)) << 16);
          unsigned hi = (unsigned)bfbits(fmaxf(t[2] + bv[2], 0.f))
                      | ((unsigned)bfbits(fmaxf(t[3] + bv[3], 0.f)) << 16);
          int byte = (row * 512 + ch * 2) ^ ((row & 7) << 4);
          uint2 pk; pk.x = lo; pk.y = hi;
          *reinterpret_cast<uint2*>((char*)hbuf + byte) = pk;
        }
      }
      __syncthreads();    // h_next visible before next layer's reads
    } else {
      // final layer: relu+bias, sum this wave's 64 rows, write partial directly
      #pragma unroll
      for (int m = 0; m < 4; ++m) {
        f32x4 bv = *reinterpret_cast<const f32x4*>(bb + wave * 64 + m * 16 + q * 4);
        f32x4 s = f32x4{0.f, 0.f, 0.f, 0.f};
        #pragma unroll
        for (int n = 0; n < 4; ++n) {
          s[0] += fmaxf(acc[m][n][0] + bv[0], 0.f);
          s[1] += fmaxf(acc[m][n][1] + bv[1], 0.f);
          s[2] += fmaxf(acc[m][n][2] + bv[2], 0.f);
          s[3] += fmaxf(acc[m][n][3] + bv[3], 0.f);
        }
        #pragma unroll
        for (int r = 0; r < 4; ++r) {
          float x = s[r];
          x += __shfl_xor(x, 1);
          x += __shfl_xor(x, 2);
          x += __shfl_xor(x, 4);
          x += __shfl_xor(x, 8);
          s[r] = x;
        }
        if (l16 == 0) {
          float4 o; o.x = s[0]; o.y = s[1]; o.z = s[2]; o.w = s[3];
          *reinterpret_cast<float4*>(partial + (size_t)wg * SZ + wave * 64 + m * 16 + q * 4) = o;
        }
      }
    }
  }
  #undef GLOAD
}

// ---------------- final reduction over (a, jhalf): 256 slices per batch ----------------
__global__ void reduce_partials(const float* __restrict__ partial, float* __restrict__ out) {
  int b = blockIdx.x;            // 16 blocks x 256 threads
  int s = threadIdx.x;
  const float* p = partial + (size_t)b * 256 * SZ + s;
  float acc = 0.f;
  for (int i = 0; i < 256; ++i) acc += p[(size_t)i * SZ];
  out[b * SZ + s] = acc;
}

extern "C" void kernel_launch(void* const* d_in, const int* in_sizes, int n_in,
                              void* d_out, int out_size, void* d_ws, size_t ws_size,
                              hipStream_t stream) {
  const float* in_ = (const float*)d_in[0];
  const float* W1  = (const float*)d_in[1];
  const float* b1  = (const float*)d_in[2];
  const float* W2  = (const float*)d_in[3];
  const float* b2  = (const float*)d_in[4];
  const float* W3  = (const float*)d_in[5];
  const float* b3  = (const float*)d_in[6];
  const float* W4  = (const float*)d_in[7];
  const float* b4  = (const float*)d_in[8];
  float* out = (float*)d_out;

  char* ws = (char*)d_ws;
  float* u       = (float*)(ws);                                 // 2 MB
  float* v       = (float*)(ws + (2u << 20));                    // 2 MB
  short* wlay    = (short*)(ws + (4u << 20));                    // 384 KB
  float* partial = (float*)(ws + (4u << 20) + (1u << 19));       // 4 MB

  uv_prep<<<MBATCH * NUMV, 256, 0, stream>>>(in_, W1, b1, u, v);
  w_prep<<<24, 256, 0, stream>>>(W2, W3, W4, wlay);
  fused_mlp<<<MBATCH * NUMV * 2, 256, 0, stream>>>(u, v, wlay, b2, b3, b4, partial);
  reduce_partials<<<MBATCH, 256, 0, stream>>>(partial, out);
}

// Round 7
// 129.679 us; speedup vs baseline: 2.3024x; 1.1529x over previous
//
#include <hip/hip_runtime.h>
#include <hip/hip_bf16.h>

using short8 = __attribute__((ext_vector_type(8))) short;
using f32x4  = __attribute__((ext_vector_type(4))) float;

#define MBATCH 16
#define NUMV   128
#define LEN    64
#define SZ     256

__device__ __forceinline__ unsigned short bfbits(float x) {
  union { float f; unsigned u; } c; c.f = x;
  return (unsigned short)((c.u + 0x8000u) >> 16);   // round-to-nearest
}

// ---------------- prep 1: u[bn][s], v[bn][s] (layer-1 factorization) ----------------
__global__ void uv_prep(const float* __restrict__ in_, const float* __restrict__ W1,
                        const float* __restrict__ b1,
                        float* __restrict__ u, float* __restrict__ v) {
  int bn = blockIdx.x;
  int n  = bn & (NUMV - 1);
  int s  = threadIdx.x;                // 256 threads
  __shared__ float xs[LEN];
  if (s < LEN) xs[s] = in_[bn * LEN + s];
  __syncthreads();
  float fn = (float)n;
  float uu = fn * W1[64 * SZ + s];
  float vv = fn * W1[129 * SZ + s] + b1[s];
  for (int c = 0; c < LEN; ++c) {
    uu = fmaf(xs[c], W1[c * SZ + s], uu);
    vv = fmaf(xs[c], W1[(65 + c) * SZ + s], vv);
  }
  u[bn * SZ + s] = uu;
  v[bn * SZ + s] = vv;
}

// ---------------- prep 2: W2/W3/W4 -> bf16 A-fragments, lane-coalesced ----------------
// frag f = ((L*4 + wv)*4 + m)*8 + kb ; 64 lanes x 16B contiguous per frag.
// lane (l16,q) of frag: Wt[ch = wv*64+m*16+l16][kb*32 + q*8 + 0..7] = W[k][ch]
__global__ void w_prep(const float* __restrict__ W2, const float* __restrict__ W3,
                       const float* __restrict__ W4, short* __restrict__ wlay) {
  int L = blockIdx.x >> 3, kb = blockIdx.x & 7;     // 24 blocks
  const float* W = (L == 0) ? W2 : (L == 1) ? W3 : W4;
  int m = threadIdx.x >> 6, lane = threadIdx.x & 63;
  int l16 = lane & 15, q = lane >> 4;
  for (int wv = 0; wv < 4; ++wv) {
    int ch = wv * 64 + m * 16 + l16;
    short8 pk;
    for (int i = 0; i < 8; ++i)
      pk[i] = (short)bfbits(W[(kb * 32 + q * 8 + i) * SZ + ch]);
    int f = ((L * 4 + wv) * 4 + m) * 8 + kb;
    reinterpret_cast<short8*>(wlay)[f * 64 + lane] = pk;
  }
}

// ---------------- main fused kernel ----------------
// One WG per (b, a, jhalf): 64 rows, 256 threads = 4 waves.
// Wave w: 64 out-channels (4 M-frags) x 64 rows (4 N-frags). A-operand lives in
// registers (4 x short8 per kb), software-pipelined 1 kb ahead from a lane-coalesced
// global layout (L2-resident). ZERO barriers inside the K-loop; hbuf read-only per layer.
// LDS = 32KB hbuf only.
__global__ __launch_bounds__(256, 2) void fused_mlp(
    const float* __restrict__ u, const float* __restrict__ v,
    const short* __restrict__ wlay,
    const float* __restrict__ b2, const float* __restrict__ b3, const float* __restrict__ b4,
    float* __restrict__ partial) {
  __shared__ __align__(16) short hbuf[64 * 256];   // 32 KB, byte ^= (row&7)<<4

  int wg = blockIdx.x;
  int b = wg >> 8, a = (wg >> 1) & 127, jh = wg & 1;
  int tid = threadIdx.x;
  int wave = tid >> 6, lane = tid & 63;
  int l16 = lane & 15, q = lane >> 4;

  const short8* wcl = reinterpret_cast<const short8*>(wlay) + lane;  // per-lane base

  short8 awA[4], awB[4];
  // preload layer-0 kb=0 fragments (latency hidden under h1 phase)
  #pragma unroll
  for (int m = 0; m < 4; ++m)
    awA[m] = wcl[(((0 * 4 + wave) * 4 + m) * 8 + 0) * 64];

  // ---- h1 = relu(u[b,j] + v[b,a]) -> bf16, swizzled row-major in LDS ----
  {
    const float4* ub = (const float4*)(u + (size_t)b * NUMV * SZ) + jh * 64 * 64;
    const float4* vb = (const float4*)(v + ((size_t)b * NUMV + a) * SZ);
    #pragma unroll
    for (int it = 0; it < 16; ++it) {
      int flat = tid + it * 256;          // over 64 rows * 64 col-quads
      int jr = flat >> 6, c4 = flat & 63;
      float4 uu = ub[jr * 64 + c4];
      float4 vv = vb[c4];
      unsigned lo = (unsigned)bfbits(fmaxf(uu.x + vv.x, 0.f))
                  | ((unsigned)bfbits(fmaxf(uu.y + vv.y, 0.f)) << 16);
      unsigned hi = (unsigned)bfbits(fmaxf(uu.z + vv.z, 0.f))
                  | ((unsigned)bfbits(fmaxf(uu.w + vv.w, 0.f)) << 16);
      int byte = (jr * 512 + c4 * 8) ^ ((jr & 7) << 4);
      uint2 pk; pk.x = lo; pk.y = hi;
      *reinterpret_cast<uint2*>((char*)hbuf + byte) = pk;
    }
  }

  __syncthreads();        // h1 visible to all waves

  #pragma unroll
  for (int L = 0; L < 3; ++L) {
    const float* bb = (L == 0) ? b2 : (L == 1) ? b3 : b4;

    f32x4 acc[4][4];
    #pragma unroll
    for (int m = 0; m < 4; ++m)
      #pragma unroll
      for (int n = 0; n < 4; ++n)
        acc[m][n] = f32x4{0.f, 0.f, 0.f, 0.f};

    #pragma unroll
    for (int kb = 0; kb < 8; ++kb) {
      // prefetch next A-fragments into the other register bank
      if (kb < 7) {
        if ((kb & 1) == 0) {
          #pragma unroll
          for (int m = 0; m < 4; ++m)
            awB[m] = wcl[(((L * 4 + wave) * 4 + m) * 8 + kb + 1) * 64];
        } else {
          #pragma unroll
          for (int m = 0; m < 4; ++m)
            awA[m] = wcl[(((L * 4 + wave) * 4 + m) * 8 + kb + 1) * 64];
        }
      } else if (L < 2) {
        #pragma unroll
        for (int m = 0; m < 4; ++m)
          awA[m] = wcl[((((L + 1) * 4 + wave) * 4 + m) * 8 + 0) * 64];
      }
      short8 bfr[4];
      #pragma unroll
      for (int n = 0; n < 4; ++n) {
        int row = n * 16 + l16;
        int byte = (row * 512 + kb * 64 + q * 16) ^ ((row & 7) << 4);
        bfr[n] = *reinterpret_cast<const short8*>((char*)hbuf + byte);
      }
      __builtin_amdgcn_s_setprio(1);
      if ((kb & 1) == 0) {
        #pragma unroll
        for (int m = 0; m < 4; ++m)
          #pragma unroll
          for (int n = 0; n < 4; ++n)
            acc[m][n] = __builtin_amdgcn_mfma_f32_16x16x32_bf16(awA[m], bfr[n], acc[m][n], 0, 0, 0);
      } else {
        #pragma unroll
        for (int m = 0; m < 4; ++m)
          #pragma unroll
          for (int n = 0; n < 4; ++n)
            acc[m][n] = __builtin_amdgcn_mfma_f32_16x16x32_bf16(awB[m], bfr[n], acc[m][n], 0, 0, 0);
      }
      __builtin_amdgcn_s_setprio(0);
    }

    __syncthreads();      // all waves done reading hbuf for this layer

    if (L < 2) {
      // epilogue: h_next[row][ch] = relu(acc+bias) -> swizzled hbuf, in place
      #pragma unroll
      for (int m = 0; m < 4; ++m) {
        f32x4 bv = *reinterpret_cast<const f32x4*>(bb + wave * 64 + m * 16 + q * 4);
        int ch = wave * 64 + m * 16 + q * 4;
        #pragma unroll
        for (int n = 0; n < 4; ++n) {
          int row = n * 16 + l16;
          f32x4 t = acc[m][n];
          unsigned lo = (unsigned)bfbits(fmaxf(t[0] + bv[0], 0.f))
                      | ((unsigned)bfbits(fmaxf(t[1] + bv[1], 0.f)) << 16);
          unsigned hi = (unsigned)bfbits(fmaxf(t[2] + bv[2], 0.f))
                      | ((unsigned)bfbits(fmaxf(t[3] + bv[3], 0.f)) << 16);
          int byte = (row * 512 + ch * 2) ^ ((row & 7) << 4);
          uint2 pk; pk.x = lo; pk.y = hi;
          *reinterpret_cast<uint2*>((char*)hbuf + byte) = pk;
        }
      }
      __syncthreads();    // h_next visible before next layer's reads
    } else {
      // final layer: relu+bias, sum this wave's 64 rows, write partial directly
      #pragma unroll
      for (int m = 0; m < 4; ++m) {
        f32x4 bv = *reinterpret_cast<const f32x4*>(bb + wave * 64 + m * 16 + q * 4);
        f32x4 s = f32x4{0.f, 0.f, 0.f, 0.f};
        #pragma unroll
        for (int n = 0; n < 4; ++n) {
          s[0] += fmaxf(acc[m][n][0] + bv[0], 0.f);
          s[1] += fmaxf(acc[m][n][1] + bv[1], 0.f);
          s[2] += fmaxf(acc[m][n][2] + bv[2], 0.f);
          s[3] += fmaxf(acc[m][n][3] + bv[3], 0.f);
        }
        #pragma unroll
        for (int r = 0; r < 4; ++r) {
          float x = s[r];
          x += __shfl_xor(x, 1);
          x += __shfl_xor(x, 2);
          x += __shfl_xor(x, 4);
          x += __shfl_xor(x, 8);
          s[r] = x;
        }
        if (l16 == 0) {
          float4 o; o.x = s[0]; o.y = s[1]; o.z = s[2]; o.w = s[3];
          *reinterpret_cast<float4*>(partial + (size_t)wg * SZ + wave * 64 + m * 16 + q * 4) = o;
        }
      }
    }
  }
}

// ---------------- final reduction over (a, jhalf): 256 slices per batch ----------------
__global__ void reduce_partials(const float* __restrict__ partial, float* __restrict__ out) {
  int b = blockIdx.x;            // 16 blocks x 256 threads
  int s = threadIdx.x;
  const float* p = partial + (size_t)b * 256 * SZ + s;
  float acc = 0.f;
  for (int i = 0; i < 256; ++i) acc += p[(size_t)i * SZ];
  out[b * SZ + s] = acc;
}

extern "C" void kernel_launch(void* const* d_in, const int* in_sizes, int n_in,
                              void* d_out, int out_size, void* d_ws, size_t ws_size,
                              hipStream_t stream) {
  const float* in_ = (const float*)d_in[0];
  const float* W1  = (const float*)d_in[1];
  const float* b1  = (const float*)d_in[2];
  const float* W2  = (const float*)d_in[3];
  const float* b2  = (const float*)d_in[4];
  const float* W3  = (const float*)d_in[5];
  const float* b3  = (const float*)d_in[6];
  const float* W4  = (const float*)d_in[7];
  const float* b4  = (const float*)d_in[8];
  float* out = (float*)d_out;

  char* ws = (char*)d_ws;
  float* u       = (float*)(ws);                                 // 2 MB
  float* v       = (float*)(ws + (2u << 20));                    // 2 MB
  short* wlay    = (short*)(ws + (4u << 20));                    // 384 KB
  float* partial = (float*)(ws + (4u << 20) + (1u << 19));       // 4 MB

  uv_prep<<<MBATCH * NUMV, 256, 0, stream>>>(in_, W1, b1, u, v);
  w_prep<<<24, 256, 0, stream>>>(W2, W3, W4, wlay);
  fused_mlp<<<MBATCH * NUMV * 2, 256, 0, stream>>>(u, v, wlay, b2, b3, b4, partial);
  reduce_partials<<<MBATCH, 256, 0, stream>>>(partial, out);
}